// Round 10
// baseline (401.916 us; speedup 1.0000x reference)
//
#include <hip/hip_runtime.h>

#define SEQ 4096
#define HID 512
#define NB  4
#define N3  1536
#define LOG2E 1.4426950408889634f

typedef _Float16 half_t;
typedef __attribute__((ext_vector_type(8))) _Float16 half8;
typedef __attribute__((ext_vector_type(4))) float f32x4;

#define GLOAD_LDS16(gp, lp) __builtin_amdgcn_global_load_lds((gp), (lp), 16, 0, 0)

#define LGKM_BARRIER()                                                       \
  asm volatile("s_waitcnt lgkmcnt(0)" ::: "memory");                         \
  __builtin_amdgcn_sched_barrier(0);                                         \
  __builtin_amdgcn_s_barrier();

// ---------------- convert x (f32) -> f16 ----------------
__global__ void k_cvt(const float* __restrict__ x, half_t* __restrict__ xh, int n4) {
  int i = blockIdx.x * blockDim.x + threadIdx.x;
  int stride = gridDim.x * blockDim.x;
  for (; i < n4; i += stride) {
    float4 v = reinterpret_cast<const float4*>(x)[i];
    union { half_t h[4]; short4 s; } u;
    u.h[0] = (half_t)v.x; u.h[1] = (half_t)v.y;
    u.h[2] = (half_t)v.z; u.h[3] = (half_t)v.w;
    reinterpret_cast<short4*>(xh)[i] = u.s;
  }
}

// ---------------- W [512][1536] f32 -> Wt [1536][512] f16 ----------------
__global__ void k_tw(const float* __restrict__ W, half_t* __restrict__ Wt) {
  __shared__ half_t tile[64][65];
  const int n0 = blockIdx.x * 64;
  const int k0 = blockIdx.y * 64;
  const int tx = threadIdx.x & 63, ty = threadIdx.x >> 6;
#pragma unroll
  for (int i = 0; i < 64; i += 4)
    tile[ty + i][tx] = (half_t)W[(size_t)(k0 + ty + i) * N3 + n0 + tx];
  __syncthreads();
#pragma unroll
  for (int i = 0; i < 64; i += 4)
    Wt[(size_t)(n0 + ty + i) * HID + k0 + tx] = tile[tx][ty + i];
}

// ---------------- QKV projection GEMM ----------------
__launch_bounds__(256)
__global__ void k_qkv(const half_t* __restrict__ xh, const half_t* __restrict__ Wt,
                      const float* __restrict__ bias,
                      half_t* __restrict__ Qh, half_t* __restrict__ Kh,
                      half_t* __restrict__ Vt) {
  __shared__ half_t sA[128 * 32];
  __shared__ half_t sB[128 * 32];
  const int t = threadIdx.x;
  const int m0 = blockIdx.y * 128;
  const int n0 = blockIdx.x * 128;
  const int lane = t & 63, wid = t >> 6;
  const int wr = (wid >> 1) * 64, wc = (wid & 1) * 64;
  const int lrow = lane & 15, lks = lane >> 4;
  const int s1 = t, s2 = t + 256;
  const int ar1 = s1 >> 2, ac1 = (s1 & 3) * 8;
  const int ar2 = s2 >> 2, ac2 = (s2 & 3) * 8;

  f32x4 acc[4][4] = {};

  for (int k0 = 0; k0 < HID; k0 += 32) {
    __syncthreads();
    GLOAD_LDS16(xh + (size_t)(m0 + ar1) * HID + k0 + ac1, &sA[s1 * 8]);
    GLOAD_LDS16(xh + (size_t)(m0 + ar2) * HID + k0 + ac2, &sA[s2 * 8]);
    GLOAD_LDS16(Wt + (size_t)(n0 + ar1) * HID + k0 + ac1, &sB[s1 * 8]);
    GLOAD_LDS16(Wt + (size_t)(n0 + ar2) * HID + k0 + ac2, &sB[s2 * 8]);
    __syncthreads();
    half8 a[4], b[4];
#pragma unroll
    for (int m = 0; m < 4; ++m)
      a[m] = *reinterpret_cast<const half8*>(&sA[(wr + m * 16 + lrow) * 32 + lks * 8]);
#pragma unroll
    for (int n = 0; n < 4; ++n)
      b[n] = *reinterpret_cast<const half8*>(&sB[(wc + n * 16 + lrow) * 32 + lks * 8]);
#pragma unroll
    for (int m = 0; m < 4; ++m)
#pragma unroll
      for (int n = 0; n < 4; ++n)
        acc[m][n] = __builtin_amdgcn_mfma_f32_16x16x32_f16(a[m], b[n], acc[m][n], 0, 0, 0);
  }

  const float scale = 0.04419417382415922f;  // 1/sqrt(512)
  const int region = n0 >> 9;  // 0=Q, 1=K, 2=V (uniform per block)
#pragma unroll
  for (int m = 0; m < 4; ++m) {
#pragma unroll
    for (int n = 0; n < 4; ++n) {
      const int col = n0 + wc + n * 16 + lrow;
#pragma unroll
      for (int r = 0; r < 4; ++r) {
        const int row = m0 + wr + m * 16 + lks * 4 + r;
        float v = acc[m][n][r] + bias[col];
        if (region == 0) {
          Qh[(size_t)row * HID + col] = (half_t)(v * scale);
        } else if (region == 1) {
          Kh[(size_t)row * HID + (col - 512)] = (half_t)v;
        } else {
          const int bb = row >> 12, ml = row & (SEQ - 1);
          Vt[((size_t)bb * HID + (col - 1024)) * SEQ + ml] = (half_t)v;
        }
      }
    }
  }
}

// ---------------- repack Vt [b][h][s] -> Vf MFMA-fragment tiles ----------------
__global__ void k_vrep(const half_t* __restrict__ Vt, half_t* __restrict__ Vf) {
  const int g = blockIdx.x * 256 + threadIdx.x;   // one half8 per thread
  const int tile = g >> 6, l = g & 63;
  const int bb = tile >> 12;
  const int kc = (tile >> 5) & 127;
  const int hg = tile & 31;
  const int h = hg * 16 + (l & 15);
  const int s = kc * 32 + (l >> 4) * 8;
  half8 v = *reinterpret_cast<const half8*>(&Vt[((size_t)bb * HID + h) * SEQ + s]);
  *reinterpret_cast<half8*>(&Vf[(size_t)tile * 512 + l * 8]) = v;
}

// ---------------- scores = Q @ K^T -> f16 Sh (packed in attn region) + partials --
__launch_bounds__(256)
__global__ void k_qk(const half_t* __restrict__ Qh, const half_t* __restrict__ Kh,
                     float* __restrict__ S, float2* __restrict__ part) {
  __shared__ half_t sA[128 * 32];
  __shared__ half_t sB[128 * 32];
  __shared__ float lm[2][128], ls[2][128];
  const int t = threadIdx.x;
  const int bz = blockIdx.z;
  const half_t* A = Qh + (size_t)bz * SEQ * HID;
  const half_t* B = Kh + (size_t)bz * SEQ * HID;
  half_t* Ch = (half_t*)(S + (size_t)bz * SEQ * SEQ);
  const int m0 = blockIdx.y * 128;
  const int n0 = blockIdx.x * 128;
  const int lane = t & 63, wid = t >> 6;
  const int wr = (wid >> 1) * 64, wc = (wid & 1) * 64;
  const int lrow = lane & 15, lks = lane >> 4;
  const int s1 = t, s2 = t + 256;
  const int ar1 = s1 >> 2, ac1 = (s1 & 3) * 8;
  const int ar2 = s2 >> 2, ac2 = (s2 & 3) * 8;

  f32x4 acc[4][4] = {};

  for (int k0 = 0; k0 < HID; k0 += 32) {
    __syncthreads();
    GLOAD_LDS16(A + (size_t)(m0 + ar1) * HID + k0 + ac1, &sA[s1 * 8]);
    GLOAD_LDS16(A + (size_t)(m0 + ar2) * HID + k0 + ac2, &sA[s2 * 8]);
    GLOAD_LDS16(B + (size_t)(n0 + ar1) * HID + k0 + ac1, &sB[s1 * 8]);
    GLOAD_LDS16(B + (size_t)(n0 + ar2) * HID + k0 + ac2, &sB[s2 * 8]);
    __syncthreads();
    half8 a[4], b[4];
#pragma unroll
    for (int m = 0; m < 4; ++m)
      a[m] = *reinterpret_cast<const half8*>(&sA[(wr + m * 16 + lrow) * 32 + lks * 8]);
#pragma unroll
    for (int n = 0; n < 4; ++n)
      b[n] = *reinterpret_cast<const half8*>(&sB[(wc + n * 16 + lrow) * 32 + lks * 8]);
#pragma unroll
    for (int m = 0; m < 4; ++m)
#pragma unroll
      for (int n = 0; n < 4; ++n)
        acc[m][n] = __builtin_amdgcn_mfma_f32_16x16x32_f16(a[m], b[n], acc[m][n], 0, 0, 0);
  }

  // f16 raw-score write into the packed Sh slots
#pragma unroll
  for (int m = 0; m < 4; ++m)
#pragma unroll
    for (int n = 0; n < 4; ++n)
#pragma unroll
      for (int r = 0; r < 4; ++r)
        Ch[(size_t)(m0 + wr + m * 16 + lks * 4 + r) * (2 * SEQ) + SEQ +
           (n0 + wc + n * 16 + lrow)] = (half_t)acc[m][n][r];

  // per-tile softmax partials
#pragma unroll
  for (int m = 0; m < 4; ++m) {
#pragma unroll
    for (int r = 0; r < 4; ++r) {
      float mx = fmaxf(fmaxf(acc[m][0][r], acc[m][1][r]),
                       fmaxf(acc[m][2][r], acc[m][3][r]));
      mx = fmaxf(mx, __shfl_xor(mx, 1));
      mx = fmaxf(mx, __shfl_xor(mx, 2));
      mx = fmaxf(mx, __shfl_xor(mx, 4));
      mx = fmaxf(mx, __shfl_xor(mx, 8));
      float s = expf(acc[m][0][r] - mx) + expf(acc[m][1][r] - mx) +
                expf(acc[m][2][r] - mx) + expf(acc[m][3][r] - mx);
      s += __shfl_xor(s, 1);
      s += __shfl_xor(s, 2);
      s += __shfl_xor(s, 4);
      s += __shfl_xor(s, 8);
      if (lrow == 0) {
        const int rr = wr + m * 16 + lks * 4 + r;
        lm[wid & 1][rr] = mx;
        ls[wid & 1][rr] = s;
      }
    }
  }
  __syncthreads();
  if (t < 128) {
    const float m0v = lm[0][t], m1v = lm[1][t];
    const float M = fmaxf(m0v, m1v);
    const float L = ls[0][t] * expf(m0v - M) + ls[1][t] * expf(m1v - M);
    part[(size_t)(bz * SEQ + m0 + t) * 32 + blockIdx.x] = make_float2(M, L);
  }
}

// ---------------- merge 32 per-tile partials per row -> (rowmax, 1/rowsum) --------
__global__ void k_lred(const float2* __restrict__ part, float2* __restrict__ stats) {
  const int row = blockIdx.x * 256 + threadIdx.x;  // [0, NB*SEQ)
  const float2* p = part + (size_t)row * 32;
  float M = -3.4028235e38f;
#pragma unroll
  for (int i = 0; i < 32; ++i) M = fmaxf(M, p[i].x);
  float L = 0.f;
#pragma unroll
  for (int i = 0; i < 32; ++i) L += p[i].y * expf(p[i].x - M);
  stats[row] = make_float2(M, 1.0f / L);
}

// ---------------- fused: read f16 Sh -> write f32 attn + opt = attn @ V ----------
// BM=32, BN=512, superchunk=128 cols (32 iters). FULLY register-pipelined:
//  - V half-superchunk double-buffer bA/bB (8 frags = 32 VGPR each). bA is
//    prefetched ACROSS the barrier (issued iter sc for sc+1); bB in-iter.
//  - Sh prefetch pr (1-iter lead, issued after its consumer -> never waited on
//    by anything younger than a full iteration).
//  - No load is ever issued after the wait that guards it; barriers lgkm-only.
// In-place safety: Sh(k) read-retired (register) before attn(k) store in the
// same step's program order; cross-iter fronts proven disjoint per-row.
__launch_bounds__(512, 4)
__global__ void k_pvn(float* __restrict__ P, const half_t* __restrict__ Vf,
                      const float2* __restrict__ stats, float* __restrict__ O) {
  __shared__ half_t sA[4][32 * 64];   // 2 superchunks x 2 halves, XOR-swizzled
  const int t = threadIdx.x;

  // bijective XCD swizzle: 512 blocks, 64 per XCD
  const int bid = blockIdx.x;
  const int sw = (bid & 7) * 64 + (bid >> 3);
  const int bz = sw >> 7;
  const int m0 = (sw & 127) * 32;

  float* Pb = P + (size_t)bz * SEQ * SEQ;
  const half_t* Vfb = Vf + (size_t)bz * 128 * 32 * 512;
  float* Ob = O + (size_t)bz * SEQ * HID;

  const int lane = t & 63, wid = t >> 6;
  const int lrow = lane & 15, lks = lane >> 4;

  // P map: thread owns 8 cols (granule pc) of row prow in each 128-col superchunk
  const int prow = t >> 4;          // 0..31
  const int pc = t & 15;            // 0..15
  const float2 st = stats[(size_t)bz * SEQ + m0 + prow];
  const float mrow2 = st.x * LOG2E, invl = st.y;

  float* const PArow = Pb + (size_t)(m0 + prow) * SEQ + pc * 8;
  const half_t* const Shrow =
      (const half_t*)(Pb + (size_t)(m0 + prow) * SEQ) + SEQ + pc * 8;

  const int schunk = pc >> 3;                   // 64-col half within superchunk
  const int sidx = prow * 64 + (((pc & 7) ^ (prow & 7)) << 3);

  // a-frag swizzled read offsets
  int aoff[2][2];
#pragma unroll
  for (int m = 0; m < 2; ++m)
#pragma unroll
    for (int kk = 0; kk < 2; ++kk) {
      const int row = m * 16 + lrow;
      aoff[m][kk] = row * 64 + (((kk * 4 + lks) ^ (row & 7)) << 3);
    }

  // V frag base: frag (q=sc*4+kc, n) at vb + ((q*32) + n)*512
  const half_t* const vb = Vfb + (size_t)(wid * 4) * 512 + lane * 8;

  f32x4 acc[2][4] = {};
  half8 bA[8], bB[8], pr;

#define PV_LOADV(BUF, Q0)                                                    \
  _Pragma("unroll")                                                          \
  for (int i = 0; i < 8; ++i)                                                \
    BUF[i] = *reinterpret_cast<const half8*>(                                \
        vb + ((size_t)((Q0) + (i >> 2)) * 32 + (i & 3)) * 512);

#define PV_MFMA_HALF(BUF, CB)                                                \
  _Pragma("unroll")                                                          \
  for (int kk = 0; kk < 2; ++kk) {                                           \
    half8 a0 = *reinterpret_cast<const half8*>(&sA[CB][aoff[0][kk]]);        \
    half8 a1 = *reinterpret_cast<const half8*>(&sA[CB][aoff[1][kk]]);        \
    _Pragma("unroll")                                                        \
    for (int n = 0; n < 4; ++n) {                                            \
      acc[0][n] = __builtin_amdgcn_mfma_f32_16x16x32_f16(a0, BUF[kk * 4 + n],\
                                                         acc[0][n], 0, 0, 0);\
      acc[1][n] = __builtin_amdgcn_mfma_f32_16x16x32_f16(a1, BUF[kk * 4 + n],\
                                                         acc[1][n], 0, 0, 0);\
    }                                                                        \
  }

  // consume pr (raw Sh of superchunk SCW): exp -> sA[SB], plain f32 attn store
#define PV_CONSUME(SB, SCW)                                                  \
  {                                                                          \
    f32x4 ev0, ev1;                                                          \
    _Pragma("unroll")                                                        \
    for (int j = 0; j < 4; ++j) {                                            \
      ev0[j] = exp2f((float)pr[j] * LOG2E - mrow2) * invl;                   \
      ev1[j] = exp2f((float)pr[j + 4] * LOG2E - mrow2) * invl;               \
    }                                                                        \
    half8 hv;                                                                \
    _Pragma("unroll")                                                        \
    for (int j = 0; j < 4; ++j) {                                            \
      hv[j] = (half_t)ev0[j];                                                \
      hv[j + 4] = (half_t)ev1[j];                                            \
    }                                                                        \
    *reinterpret_cast<half8*>(&sA[(SB) * 2 + schunk][sidx]) = hv;            \
    *reinterpret_cast<f32x4*>(PArow + (SCW) * 128) = ev0;                    \
    *reinterpret_cast<f32x4*>(PArow + (SCW) * 128 + 4) = ev1;                \
  }

  // ---- prologue: V(0,h0)->bA; consume Sh(0); issue pr <- Sh(1) ----
  {
    PV_LOADV(bA, 0);
    pr = *reinterpret_cast<const half8*>(Shrow);
    PV_CONSUME(0, 0);
    pr = *reinterpret_cast<const half8*>(Shrow + 128);
    LGKM_BARRIER();
  }

  for (int sc = 0; sc < 32; ++sc) {
    const int base = (sc & 1) * 2;
    // 1: issue V(sc, h1) -> bB
    PV_LOADV(bB, sc * 4 + 2);
    __builtin_amdgcn_sched_barrier(0);
    // 2: MFMA h0 from bA (prefetched across the barrier last iter)
    PV_MFMA_HALF(bA, base);
    // 3: issue V(sc+1, h0) -> bA (rides across the barrier)
    if (sc + 1 < 32) {
      PV_LOADV(bA, (sc + 1) * 4);
    }
    __builtin_amdgcn_sched_barrier(0);
    // 4: MFMA h1 from bB (in flight during h0)
    PV_MFMA_HALF(bB, base + 1);
    // 5: consume Sh(sc+1) (loaded last iter) -> exp, sA[(sc+1)&1], attn store;
    //    then issue pr <- Sh(sc+2)
    if (sc + 1 < 32) {
      PV_CONSUME((sc + 1) & 1, sc + 1);
      if (sc + 2 < 32)
        pr = *reinterpret_cast<const half8*>(Shrow + (sc + 2) * 128);
    }
    LGKM_BARRIER();
  }

#pragma unroll
  for (int m = 0; m < 2; ++m)
#pragma unroll
    for (int n = 0; n < 4; ++n)
#pragma unroll
      for (int r = 0; r < 4; ++r)
        Ob[(size_t)(m0 + m * 16 + lks * 4 + r) * HID + (wid * 64 + n * 16 + lrow)] =
            acc[m][n][r];
}

extern "C" void kernel_launch(void* const* d_in, const int* in_sizes, int n_in,
                              void* d_out, int out_size, void* d_ws, size_t ws_size,
                              hipStream_t stream) {
  const float* x = (const float*)d_in[0];     // [4,4096,512]
  const float* W = (const float*)d_in[1];     // [512,1536]
  const float* bias = (const float*)d_in[2];  // [1536]
  float* opt = (float*)d_out;                        // [4*4096*512]
  float* attn = opt + (size_t)NB * SEQ * HID;        // [4*4096*4096]

  half_t* xh = (half_t*)d_ws;                        // 16384*512
  half_t* Wt = xh + (size_t)NB * SEQ * HID;          // 1536*512
  half_t* Qh = Wt + (size_t)N3 * HID;                // 16384*512 (scale folded)
  half_t* Kh = Qh + (size_t)NB * SEQ * HID;          // 16384*512
  half_t* Vt = Kh + (size_t)NB * SEQ * HID;          // 4*[512][4096] transposed
  half_t* Vf = Vt + (size_t)NB * HID * SEQ;          // fragment-packed V (16 MB)
  float2* part = (float2*)(Vf + (size_t)NB * HID * SEQ);  // [16384][32]
  float2* stats = part + (size_t)NB * SEQ * 32;           // [16384]

  k_cvt<<<2048, 256, 0, stream>>>(x, xh, NB * SEQ * HID / 4);
  k_tw<<<dim3(N3 / 64, HID / 64), 256, 0, stream>>>(W, Wt);
  k_qkv<<<dim3(N3 / 128, NB * SEQ / 128), 256, 0, stream>>>(xh, Wt, bias, Qh, Kh, Vt);
  k_vrep<<<NB * HID * SEQ / 8 / 256, 256, 0, stream>>>(Vt, Vf);
  k_qk<<<dim3(SEQ / 128, SEQ / 128, NB), 256, 0, stream>>>(Qh, Kh, attn, part);
  k_lred<<<NB * SEQ / 256, 256, 0, stream>>>(part, stats);
  k_pvn<<<512, 512, 0, stream>>>(attn, Vf, stats, opt);
}